// Round 1
// baseline (2713.920 us; speedup 1.0000x reference)
//
#include <hip/hip_runtime.h>
#include <stdint.h>
#include <string.h>

// Problem constants (B,S,D)=(2,1024,2048), H=16 KV=8 HD=128, E=8 A=2 I=4096
#define T_TOK 2048
#define D_MODEL 2048
#define S_SEQ 1024
#define NB 2
#define NH 16
#define NKV 8
#define HDIM 128
#define NE 8
#define NI 4096

typedef __attribute__((ext_vector_type(8))) short short8;
typedef __attribute__((ext_vector_type(4))) float floatx4;

__device__ __forceinline__ ushort f2bf(float f) {
  union { float f; uint32_t u; } x; x.f = f;
  uint32_t u = x.u;
  uint32_t r = (u + 0x7fffu + ((u >> 16) & 1u)) >> 16;
  return (ushort)r;
}
__device__ __forceinline__ float bf2f(ushort h) {
  union { uint32_t u; float f; } x; x.u = ((uint32_t)h) << 16; return x.f;
}

// ---------------- RMSNorm: f32 in -> bf16 out (+ optional f32 copy) ----------
__global__ void rmsnorm_k(const float* __restrict__ x, const float* __restrict__ w,
                          ushort* __restrict__ obf, float* __restrict__ of32) {
  const int t = blockIdx.x, tid = threadIdx.x;
  const float* xr = x + (size_t)t * D_MODEL;
  float ss = 0.f;
  for (int k = tid; k < D_MODEL; k += 256) { float v = xr[k]; ss += v * v; }
  #pragma unroll
  for (int o = 32; o; o >>= 1) ss += __shfl_xor(ss, o);
  __shared__ float wsum[4];
  if ((tid & 63) == 0) wsum[tid >> 6] = ss;
  __syncthreads();
  float tot = wsum[0] + wsum[1] + wsum[2] + wsum[3];
  float r = rsqrtf(tot * (1.0f / D_MODEL) + 1e-5f);
  for (int k = tid; k < D_MODEL; k += 256) {
    float v = xr[k] * r * w[k];
    obf[(size_t)t * D_MODEL + k] = f2bf(v);
    if (of32) of32[(size_t)t * D_MODEL + k] = v;
  }
}

// ---------------- Generic 128x128 MFMA GEMM: C = A * B^T ---------------------
// A: bf16 (optionally row-gathered), B: f32 (converted in staging) or bf16.
// Batched over z (attention) or expert-segmented (MoE).
struct GP {
  const ushort* A;
  const void* B;
  float* Cf; ushort* Cb; const float* X;
  const int* expOff; const int* gatherIdx;
  const int* scTok; const int* scSlot;
  long aOffB, aOffH, bOffB, bOffH, cOffB, cOffH;
  long bExpStride;
  int lda, ldb, ldc, K, M, zmod, rep;
  int bIsF32, epi, causalSkip, scLd;
  float alpha;
};

__global__ void gemm_uni(GP gp) {
  __shared__ ushort As[128 * 32];
  __shared__ ushort Bs[128 * 32];
  const int tid = threadIdx.x;
  const int tm = blockIdx.y, tn = blockIdx.x;
  int rowBase = 0, cnt = gp.M;
  long aB = 0, bB = 0, cB = 0;
  if (gp.expOff) {
    int e = blockIdx.z;
    rowBase = gp.expOff[e];
    cnt = gp.expOff[e + 1] - rowBase;
    if (cnt <= 0 || tm * 128 >= cnt) return;
    bB = (long)e * gp.bExpStride;
  } else {
    int z = blockIdx.z;
    int zb = z / gp.zmod, zh = z - zb * gp.zmod;
    aB = zb * gp.aOffB + (long)zh * gp.aOffH;
    bB = zb * gp.bOffB + (long)(zh / gp.rep) * gp.bOffH;
    cB = zb * gp.cOffB + (long)zh * gp.cOffH;
    if (gp.causalSkip && tn * 128 > tm * 128 + 127) return;  // fully-masked tile
  }
  floatx4 acc[4][4] = {};
  const int lane = tid & 63;
  const int w = tid >> 6;
  const int wm = (w & 1) << 6, wn = (w >> 1) << 6;
  const int r16 = lane & 15, kq = (lane >> 4) << 3;

  for (int k0 = 0; k0 < gp.K; k0 += 32) {
    // stage A tile: 128 rows x 32 cols bf16, 512 x 16B chunks
    #pragma unroll
    for (int i = 0; i < 2; ++i) {
      int c = i * 256 + tid;
      int r = c >> 2;
      int colE = (c & 3) << 3;
      int lr = tm * 128 + r; if (lr > cnt - 1) lr = cnt - 1;  // clamp partial tiles
      long arow = gp.gatherIdx ? (long)gp.gatherIdx[rowBase + lr] : (long)(rowBase + lr);
      const ushort* src = gp.A + aB + arow * (long)gp.lda + k0 + colE;
      *(int4*)&As[r * 32 + colE] = *(const int4*)src;
    }
    // stage B tile
    if (gp.bIsF32) {
      const float* Bf = (const float*)gp.B;
      #pragma unroll
      for (int i = 0; i < 4; ++i) {
        int c = i * 256 + tid;            // 1024 x 16B (float4) chunks
        int r = c >> 3;
        int colE = (c & 7) << 2;
        const float* src = Bf + bB + (long)(tn * 128 + r) * gp.ldb + k0 + colE;
        float4 v = *(const float4*)src;
        uint32_t lo = (uint32_t)f2bf(v.x) | ((uint32_t)f2bf(v.y) << 16);
        uint32_t hi = (uint32_t)f2bf(v.z) | ((uint32_t)f2bf(v.w) << 16);
        uint2 pk; pk.x = lo; pk.y = hi;
        *(uint2*)&Bs[r * 32 + colE] = pk;
      }
    } else {
      const ushort* Bb = (const ushort*)gp.B;
      #pragma unroll
      for (int i = 0; i < 2; ++i) {
        int c = i * 256 + tid;
        int r = c >> 2;
        int colE = (c & 3) << 3;
        const ushort* src = Bb + bB + (long)(tn * 128 + r) * gp.ldb + k0 + colE;
        *(int4*)&Bs[r * 32 + colE] = *(const int4*)src;
      }
    }
    __syncthreads();
    short8 af[4], bfr[4];
    #pragma unroll
    for (int i = 0; i < 4; ++i) af[i] = *(const short8*)&As[(wm + i * 16 + r16) * 32 + kq];
    #pragma unroll
    for (int j = 0; j < 4; ++j) bfr[j] = *(const short8*)&Bs[(wn + j * 16 + r16) * 32 + kq];
    #pragma unroll
    for (int i = 0; i < 4; ++i)
      #pragma unroll
      for (int j = 0; j < 4; ++j)
        acc[i][j] = __builtin_amdgcn_mfma_f32_16x16x32_bf16(af[i], bfr[j], acc[i][j], 0, 0, 0);
    __syncthreads();
  }
  // epilogue: C/D layout col=lane&15, row=(lane>>4)*4+r
  const int col = lane & 15, rq = (lane >> 4) << 2;
  #pragma unroll
  for (int i = 0; i < 4; ++i) {
    #pragma unroll
    for (int j = 0; j < 4; ++j) {
      #pragma unroll
      for (int r = 0; r < 4; ++r) {
        int gm = tm * 128 + wm + i * 16 + rq + r;
        if (gm >= cnt) continue;
        int gn = tn * 128 + wn + j * 16 + col;
        float v = acc[i][j][r] * gp.alpha;
        long cidx = cB + (long)(rowBase + gm) * gp.ldc + gn;
        if (gp.epi == 0) gp.Cf[cidx] = v;
        else if (gp.epi == 1) gp.Cb[cidx] = f2bf(v);
        else if (gp.epi == 2) gp.Cf[cidx] = v + gp.X[cidx];
        else {
          int m = rowBase + gm;
          int tok = gp.scTok[m], slot = gp.scSlot[m];
          gp.Cf[((long)tok * 2 + slot) * gp.scLd + gn] = v;
        }
      }
    }
  }
}

// ---------------- RoPE in place on bf16 (T x nH x 128), pairs (2d,2d+1) ------
__global__ void rope_k(ushort* __restrict__ t, const float* __restrict__ fc, int nH, int total) {
  int gid = blockIdx.x * 256 + threadIdx.x;
  if (gid >= total) return;
  int d = gid & 63;
  int rem = gid >> 6;
  int hh = rem % nH;
  int tok = rem / nH;
  int s = tok & (S_SEQ - 1);
  float c = fc[(s * 64 + d) * 2], sn = fc[(s * 64 + d) * 2 + 1];
  uint32_t* p = (uint32_t*)(t + ((size_t)tok * nH + hh) * HDIM + d * 2);
  uint32_t v = *p;
  float a = bf2f((ushort)(v & 0xffff)), b = bf2f((ushort)(v >> 16));
  *p = (uint32_t)f2bf(a * c - b * sn) | ((uint32_t)f2bf(a * sn + b * c) << 16);
}

// ---------------- V transpose: (b,s,kv,d) -> (b,kv,d,s) ----------------------
__global__ void vt_k(const ushort* __restrict__ v, ushort* __restrict__ vT) {
  int gid = blockIdx.x * 256 + threadIdx.x;  // 2M
  int s = gid & 1023;
  int rem = gid >> 10;
  int d = rem & 127;
  int kv = (rem >> 7) & 7;
  int b = rem >> 10;
  vT[gid] = v[((size_t)(b * S_SEQ + s)) * (NKV * HDIM) + kv * HDIM + d];
}

// ---------------- causal softmax: f32 scores -> bf16 probs -------------------
__global__ void softmax_causal(const float* __restrict__ sc, ushort* __restrict__ pr) {
  int w = threadIdx.x >> 6, lane = threadIdx.x & 63;
  long row = (long)blockIdx.x * 4 + w;  // (b*H+h)*S + q
  int q = row & (S_SEQ - 1); long z = row >> 10;
  const float* srow = sc + (z << 20) + (long)q * S_SEQ;
  ushort* prow = pr + (z << 20) + (long)q * S_SEQ;
  int len = q + 1;
  float m = -1e30f;
  for (int k = lane; k < len; k += 64) m = fmaxf(m, srow[k]);
  #pragma unroll
  for (int o = 32; o; o >>= 1) m = fmaxf(m, __shfl_xor(m, o));
  float s = 0.f;
  for (int k = lane; k < len; k += 64) s += __expf(srow[k] - m);
  #pragma unroll
  for (int o = 32; o; o >>= 1) s += __shfl_xor(s, o);
  float inv = 1.0f / s;
  for (int k = lane; k < S_SEQ; k += 64)
    prow[k] = (k < len) ? f2bf(__expf(srow[k] - m) * inv) : (ushort)0;
}

// ---------------- gate: fp32 scores, softmax, top-2 (lowest-index ties) ------
__global__ void gate_topk(const float* __restrict__ f, const float* __restrict__ gw,
                          int* __restrict__ e0, int* __restrict__ e1,
                          float* __restrict__ g0, float* __restrict__ g1) {
  int t = blockIdx.x, lane = threadIdx.x;  // 64 threads
  const float* xr = f + (size_t)t * D_MODEL;
  float acc[NE];
  #pragma unroll
  for (int e = 0; e < NE; ++e) acc[e] = 0.f;
  for (int k = lane; k < D_MODEL; k += 64) {
    float xv = xr[k];
    #pragma unroll
    for (int e = 0; e < NE; ++e) acc[e] += xv * gw[e * D_MODEL + k];
  }
  #pragma unroll
  for (int e = 0; e < NE; ++e) {
    #pragma unroll
    for (int o = 32; o; o >>= 1) acc[e] += __shfl_xor(acc[e], o);
  }
  if (lane == 0) {
    int b0 = 0;
    #pragma unroll
    for (int e = 1; e < NE; ++e) if (acc[e] > acc[b0]) b0 = e;
    int b1 = -1;
    #pragma unroll
    for (int e = 0; e < NE; ++e) { if (e == b0) continue; if (b1 < 0 || acc[e] > acc[b1]) b1 = e; }
    float z1 = __expf(acc[b1] - acc[b0]);  // renormalized top-2 softmax
    float s = 1.f + z1;
    e0[t] = b0; e1[t] = b1; g0[t] = 1.f / s; g1[t] = z1 / s;
  }
}

// ---------------- routing: counts -> offsets -> permutation ------------------
__global__ void route_build(const int* __restrict__ e0, const int* __restrict__ e1,
                            int* __restrict__ expOff, int* __restrict__ permTok,
                            int* __restrict__ permSlot) {
  __shared__ int cnt[NE]; __shared__ int base[NE];
  int tid = threadIdx.x;
  if (tid < NE) cnt[tid] = 0;
  __syncthreads();
  for (int t = tid; t < T_TOK; t += 256) {
    atomicAdd(&cnt[e0[t]], 1);
    atomicAdd(&cnt[e1[t]], 1);
  }
  __syncthreads();
  if (tid == 0) {
    int o = 0;
    for (int e = 0; e < NE; ++e) { base[e] = o; expOff[e] = o; o += cnt[e]; }
    expOff[NE] = o;
  }
  __syncthreads();
  if (tid < NE) cnt[tid] = 0;
  __syncthreads();
  for (int t = tid; t < T_TOK; t += 256) {
    int p0 = base[e0[t]] + atomicAdd(&cnt[e0[t]], 1);
    permTok[p0] = t; permSlot[p0] = 0;
    int p1 = base[e1[t]] + atomicAdd(&cnt[e1[t]], 1);
    permTok[p1] = t; permSlot[p1] = 1;
  }
}

// ---------------- silu(x1)*x3 -> bf16 ----------------------------------------
__global__ void silu_mul_k(const float* __restrict__ x1, const float* __restrict__ x3,
                           ushort* __restrict__ h13) {
  size_t gid = (size_t)blockIdx.x * 256 + threadIdx.x;
  float a = x1[gid], b = x3[gid];
  float s = a / (1.f + __expf(-a));
  h13[gid] = f2bf(s * b);
}

// ---------------- out = h + g0*moe[slot0] + g1*moe[slot1] --------------------
__global__ void combine_k(const float* __restrict__ h, const float* __restrict__ moe,
                          const float* __restrict__ g0, const float* __restrict__ g1,
                          float* __restrict__ out) {
  int gid = blockIdx.x * 256 + threadIdx.x;
  int d = gid & (D_MODEL - 1);
  int t = gid >> 11;
  out[gid] = h[gid] + g0[t] * moe[((size_t)t * 2) * D_MODEL + d]
                    + g1[t] * moe[((size_t)t * 2 + 1) * D_MODEL + d];
}

extern "C" void kernel_launch(void* const* d_in, const int* in_sizes, int n_in,
                              void* d_out, int out_size, void* d_ws, size_t ws_size,
                              hipStream_t stream) {
  const float* x   = (const float*)d_in[0];
  const float* fc  = (const float*)d_in[1];
  // d_in[2] = mask: exactly causal, applied structurally
  const float* anw = (const float*)d_in[3];
  const float* fnw = (const float*)d_in[4];
  const float* wq  = (const float*)d_in[5];
  const float* wk  = (const float*)d_in[6];
  const float* wv  = (const float*)d_in[7];
  const float* wo  = (const float*)d_in[8];
  const float* gw  = (const float*)d_in[9];
  const float* w1  = (const float*)d_in[10];
  const float* w2  = (const float*)d_in[11];
  const float* w3  = (const float*)d_in[12];
  float* out = (float*)d_out;

  char* base = (char*)d_ws;
  size_t off = 0;
  auto carve = [&](size_t bytes) -> void* {
    void* r = base + off;
    off += (bytes + 255) & ~(size_t)255;
    return r;
  };
  ushort* hn    = (ushort*)carve((size_t)T_TOK * D_MODEL * 2);
  ushort* qb    = (ushort*)carve((size_t)T_TOK * NH * HDIM * 2);
  ushort* kb    = (ushort*)carve((size_t)T_TOK * NKV * HDIM * 2);
  ushort* vb    = (ushort*)carve((size_t)T_TOK * NKV * HDIM * 2);
  ushort* vtb   = (ushort*)carve((size_t)T_TOK * NKV * HDIM * 2);
  float*  sc    = (float*)carve((size_t)NB * NH * S_SEQ * S_SEQ * 4);
  ushort* pb    = (ushort*)carve((size_t)NB * NH * S_SEQ * S_SEQ * 2);
  ushort* attn  = (ushort*)carve((size_t)T_TOK * NH * HDIM * 2);
  float*  hbuf  = (float*)carve((size_t)T_TOK * D_MODEL * 4);
  ushort* fb    = (ushort*)carve((size_t)T_TOK * D_MODEL * 2);
  float*  ff    = (float*)carve((size_t)T_TOK * D_MODEL * 4);
  int*    e0    = (int*)carve(T_TOK * 4);
  int*    e1    = (int*)carve(T_TOK * 4);
  float*  g0    = (float*)carve(T_TOK * 4);
  float*  g1    = (float*)carve(T_TOK * 4);
  int*    expOff= (int*)carve((NE + 1) * 4);
  int*    pTok  = (int*)carve(T_TOK * 2 * 4);
  int*    pSlot = (int*)carve(T_TOK * 2 * 4);
  float*  x1    = (float*)carve((size_t)T_TOK * 2 * NI * 4);
  float*  x3    = (float*)carve((size_t)T_TOK * 2 * NI * 4);
  ushort* h13   = (ushort*)carve((size_t)T_TOK * 2 * NI * 2);
  float*  moeO  = (float*)carve((size_t)T_TOK * 2 * D_MODEL * 4);
  (void)ws_size; (void)in_sizes; (void)n_in; (void)out_size;

  GP g;
  auto reset = [&]() { memset(&g, 0, sizeof(GP)); g.zmod = 1; g.rep = 1; g.alpha = 1.f; };

  // 1) attn RMSNorm -> hn (bf16)
  rmsnorm_k<<<T_TOK, 256, 0, stream>>>(x, anw, hn, nullptr);

  // 2) Q/K/V projections (B = f32 weights, converted in staging)
  reset();
  g.A = hn; g.lda = D_MODEL; g.K = D_MODEL; g.M = T_TOK;
  g.B = wq; g.bIsF32 = 1; g.ldb = D_MODEL;
  g.epi = 1; g.Cb = qb; g.ldc = NH * HDIM;
  gemm_uni<<<dim3(16, 16, 1), 256, 0, stream>>>(g);
  g.B = wk; g.Cb = kb; g.ldc = NKV * HDIM;
  gemm_uni<<<dim3(8, 16, 1), 256, 0, stream>>>(g);
  g.B = wv; g.Cb = vb;
  gemm_uni<<<dim3(8, 16, 1), 256, 0, stream>>>(g);

  // 3) RoPE on q,k; transpose v
  rope_k<<<(T_TOK * NH * 64) / 256, 256, 0, stream>>>(qb, fc, NH, T_TOK * NH * 64);
  rope_k<<<(T_TOK * NKV * 64) / 256, 256, 0, stream>>>(kb, fc, NKV, T_TOK * NKV * 64);
  vt_k<<<(T_TOK * NKV * HDIM) / 256, 256, 0, stream>>>(vb, vtb);

  // 4) scores = Q K^T / sqrt(HD), causal tiles skipped
  reset();
  g.A = qb; g.lda = NH * HDIM; g.K = HDIM; g.M = S_SEQ;
  g.aOffB = (long)S_SEQ * NH * HDIM; g.aOffH = HDIM;
  g.B = kb; g.bIsF32 = 0; g.ldb = NKV * HDIM;
  g.bOffB = (long)S_SEQ * NKV * HDIM; g.bOffH = HDIM;
  g.zmod = NH; g.rep = NH / NKV;
  g.epi = 0; g.Cf = sc; g.ldc = S_SEQ;
  g.cOffB = (long)NH * S_SEQ * S_SEQ; g.cOffH = (long)S_SEQ * S_SEQ;
  g.alpha = 0.08838834764831843f;  // 1/sqrt(128)
  g.causalSkip = 1;
  gemm_uni<<<dim3(8, 8, NB * NH), 256, 0, stream>>>(g);

  // 5) causal softmax -> bf16 probs
  softmax_causal<<<NB * NH * S_SEQ / 4, 256, 0, stream>>>(sc, pb);

  // 6) attn = P V   (B operand = V^T tiles)
  reset();
  g.A = pb; g.lda = S_SEQ; g.K = S_SEQ; g.M = S_SEQ;
  g.aOffB = (long)NH * S_SEQ * S_SEQ; g.aOffH = (long)S_SEQ * S_SEQ;
  g.B = vtb; g.bIsF32 = 0; g.ldb = S_SEQ;
  g.bOffB = (long)NKV * HDIM * S_SEQ; g.bOffH = (long)HDIM * S_SEQ;
  g.zmod = NH; g.rep = NH / NKV;
  g.epi = 1; g.Cb = attn; g.ldc = NH * HDIM;
  g.cOffB = (long)S_SEQ * NH * HDIM; g.cOffH = HDIM;
  gemm_uni<<<dim3(1, 8, NB * NH), 256, 0, stream>>>(g);

  // 7) h = x + attn @ wo^T
  reset();
  g.A = attn; g.lda = NH * HDIM; g.K = NH * HDIM; g.M = T_TOK;
  g.B = wo; g.bIsF32 = 1; g.ldb = NH * HDIM;
  g.epi = 2; g.Cf = hbuf; g.X = x; g.ldc = D_MODEL;
  gemm_uni<<<dim3(16, 16, 1), 256, 0, stream>>>(g);

  // 8) ffn RMSNorm -> f (bf16 for experts, f32 for gate)
  rmsnorm_k<<<T_TOK, 256, 0, stream>>>(hbuf, fnw, fb, ff);

  // 9) gate + routing (fp32 to keep top-k selection exact)
  gate_topk<<<T_TOK, 64, 0, stream>>>(ff, gw, e0, e1, g0, g1);
  route_build<<<1, 256, 0, stream>>>(e0, e1, expOff, pTok, pSlot);

  // 10) expert GEMMs: x1 = xe w1^T, x3 = xe w3^T  (gathered A rows)
  reset();
  g.A = fb; g.lda = D_MODEL; g.K = D_MODEL;
  g.expOff = expOff; g.gatherIdx = pTok;
  g.B = w1; g.bIsF32 = 1; g.ldb = D_MODEL; g.bExpStride = (long)NI * D_MODEL;
  g.epi = 0; g.Cf = x1; g.ldc = NI;
  gemm_uni<<<dim3(NI / 128, 16, NE), 256, 0, stream>>>(g);
  g.B = w3; g.Cf = x3;
  gemm_uni<<<dim3(NI / 128, 16, NE), 256, 0, stream>>>(g);

  // 11) h13 = silu(x1)*x3 (bf16)
  silu_mul_k<<<(T_TOK * 2 * NI) / 256, 256, 0, stream>>>(x1, x3, h13);

  // 12) moe rows = h13 @ w2^T, scattered to (token,slot)
  reset();
  g.A = h13; g.lda = NI; g.K = NI;
  g.expOff = expOff; g.gatherIdx = nullptr;
  g.B = w2; g.bIsF32 = 1; g.ldb = NI; g.bExpStride = (long)D_MODEL * NI;
  g.epi = 3; g.Cf = moeO; g.ldc = D_MODEL;
  g.scTok = pTok; g.scSlot = pSlot; g.scLd = D_MODEL;
  gemm_uni<<<dim3(D_MODEL / 128, 16, NE), 256, 0, stream>>>(g);

  // 13) out = h + weighted expert outputs
  combine_k<<<(T_TOK * D_MODEL) / 256, 256, 0, stream>>>(hbuf, moeO, g0, g1, out);
}